// Round 1
// baseline (695.761 us; speedup 1.0000x reference)
//
#include <hip/hip_runtime.h>

#define NN   100000   // nodes
#define EE   1600000  // edges
#define DD   64       // feature dim
#define DOUT 16       // output dim
#define CAP  64       // max in-degree slots per node (Poisson(16): P(deg>64) ~ 1e-18)

// ---------------------------------------------------------------------------
// Build padded CSR-by-dst: cnt[d] = in-degree, csr[d*CAP + i] = i-th source.
// ---------------------------------------------------------------------------
__global__ __launch_bounds__(256) void k_build(const int* __restrict__ ei,
                                               int* __restrict__ cnt,
                                               int* __restrict__ csr) {
    int e = blockIdx.x * 256 + threadIdx.x;
    if (e >= EE) return;
    int s = ei[e];         // src row
    int d = ei[EE + e];    // dst row
    int pos = atomicAdd(&cnt[d], 1);
    if (pos < CAP) csr[d * CAP + pos] = s;
}

__global__ __launch_bounds__(256) void k_dinv(const int* __restrict__ cnt,
                                              float* __restrict__ dinv) {
    int n = blockIdx.x * 256 + threadIdx.x;
    if (n < NN) dinv[n] = rsqrtf((float)cnt[n] + 1.0f);
}

// ---------------------------------------------------------------------------
// h'[n][j] = (sum_k in[n][k] * W[k][j]) * dinv[n]
// One wave per ROWS rows; lane j holds W column j in VGPRs; input row read as
// wave-uniform float4 (L1 broadcast). 64 v_fma per row.
// ---------------------------------------------------------------------------
template <int ROWS>
__global__ __launch_bounds__(256) void k_gemm_scale(const float* __restrict__ in,
                                                    const float* __restrict__ W,
                                                    const float* __restrict__ dinv,
                                                    float* __restrict__ out) {
    const int lane = threadIdx.x & 63;
    const int wv   = threadIdx.x >> 6;
    float Wreg[DD];
#pragma unroll
    for (int k = 0; k < DD; ++k) Wreg[k] = W[k * DD + lane];  // coalesced

    int wid  = blockIdx.x * 4 + wv;
    int base = wid * ROWS;
    for (int r = 0; r < ROWS; ++r) {
        int n = base + r;
        if (n >= NN) return;
        const float4* row = (const float4*)(in + (size_t)n * DD);
        float acc = 0.f;
#pragma unroll
        for (int kk = 0; kk < DD / 4; ++kk) {
            float4 q = row[kk];  // uniform address -> broadcast
            acc = fmaf(q.x, Wreg[4 * kk + 0], acc);
            acc = fmaf(q.y, Wreg[4 * kk + 1], acc);
            acc = fmaf(q.z, Wreg[4 * kk + 2], acc);
            acc = fmaf(q.w, Wreg[4 * kk + 3], acc);
        }
        out[(size_t)n * DD + lane] = acc * dinv[n];
    }
}

// ---------------------------------------------------------------------------
// out[n] = relu(dinv[n] * (h'[n] + sum_{src in csr[n]} h'[src]) + bias)
// One wave per node. Source indices: one coalesced load + __shfl broadcast.
// Each gather = 64 lanes x 4B = fully coalesced 256B row read.
// ---------------------------------------------------------------------------
__global__ __launch_bounds__(256) void k_agg(const float* __restrict__ hp,
                                             const int* __restrict__ csr,
                                             const int* __restrict__ cnt,
                                             const float* __restrict__ dinv,
                                             const float* __restrict__ bias,
                                             float* __restrict__ out) {
    const int lane = threadIdx.x & 63;
    const int wv   = threadIdx.x >> 6;
    int n = blockIdx.x * 4 + wv;
    if (n >= NN) return;

    int my = csr[(size_t)n * CAP + lane];  // coalesced row of source indices
    int c  = cnt[n];
    if (c > CAP) c = CAP;

    float acc = hp[(size_t)n * DD + lane];  // self-loop term (h' already * dinv)
    int i = 0;
    for (; i + 4 <= c; i += 4) {  // 4 outstanding gathers for MLP
        int s0 = __shfl(my, i);
        int s1 = __shfl(my, i + 1);
        int s2 = __shfl(my, i + 2);
        int s3 = __shfl(my, i + 3);
        float a0 = hp[(size_t)s0 * DD + lane];
        float a1 = hp[(size_t)s1 * DD + lane];
        float a2 = hp[(size_t)s2 * DD + lane];
        float a3 = hp[(size_t)s3 * DD + lane];
        acc += (a0 + a1) + (a2 + a3);
    }
    for (; i < c; ++i) {
        int s = __shfl(my, i);
        acc += hp[(size_t)s * DD + lane];
    }
    out[(size_t)n * DD + lane] = fmaxf(fmaf(dinv[n], acc, bias[lane]), 0.f);
}

// ---------------------------------------------------------------------------
// Fused FFN: out = relu(h @ Wf1 + bf1) @ Wf2 + bf2.
// First matmul like k_gemm_scale. Second: lane (q,jj) computes quarter-K
// partial of out feature jj, reduced across quarters with 2 shfl_xor.
// ---------------------------------------------------------------------------
template <int ROWS>
__global__ __launch_bounds__(256) void k_ffn(const float* __restrict__ in,
                                             const float* __restrict__ Wf1,
                                             const float* __restrict__ bf1,
                                             const float* __restrict__ Wf2,
                                             const float* __restrict__ bf2,
                                             float* __restrict__ out) {
    const int lane = threadIdx.x & 63;
    const int wv   = threadIdx.x >> 6;
    const int q    = lane >> 4;   // quarter 0..3
    const int jj   = lane & 15;   // output feature

    float W1reg[DD];
#pragma unroll
    for (int k = 0; k < DD; ++k) W1reg[k] = Wf1[k * DD + lane];
    float W2reg[16];
#pragma unroll
    for (int kk = 0; kk < 16; ++kk) W2reg[kk] = Wf2[(q * 16 + kk) * DOUT + jj];
    float b1v = bf1[lane];

    int wid  = blockIdx.x * 4 + wv;
    int base = wid * ROWS;
    for (int r = 0; r < ROWS; ++r) {
        int n = base + r;
        if (n >= NN) return;
        const float4* row = (const float4*)(in + (size_t)n * DD);
        float acc = b1v;
#pragma unroll
        for (int kk = 0; kk < DD / 4; ++kk) {
            float4 qd = row[kk];
            acc = fmaf(qd.x, W1reg[4 * kk + 0], acc);
            acc = fmaf(qd.y, W1reg[4 * kk + 1], acc);
            acc = fmaf(qd.z, W1reg[4 * kk + 2], acc);
            acc = fmaf(qd.w, W1reg[4 * kk + 3], acc);
        }
        float t = fmaxf(acc, 0.f);  // lane j holds t_j

        float p = 0.f;
#pragma unroll
        for (int kk = 0; kk < 16; ++kk) {
            float tk = __shfl(t, q * 16 + kk);
            p = fmaf(tk, W2reg[kk], p);
        }
        p += __shfl_xor(p, 16);
        p += __shfl_xor(p, 32);
        if (q == 0) out[(size_t)n * DOUT + jj] = p + bf2[jj];
    }
}

// ---------------------------------------------------------------------------
extern "C" void kernel_launch(void* const* d_in, const int* in_sizes, int n_in,
                              void* d_out, int out_size, void* d_ws, size_t ws_size,
                              hipStream_t stream) {
    const float* x   = (const float*)d_in[0];
    const int*   ei  = (const int*)d_in[1];
    const float* W1  = (const float*)d_in[2];
    const float* b1  = (const float*)d_in[3];
    const float* W2  = (const float*)d_in[4];
    const float* b2  = (const float*)d_in[5];
    const float* W3  = (const float*)d_in[6];
    const float* b3  = (const float*)d_in[7];
    const float* Wf1 = (const float*)d_in[8];
    const float* bf1 = (const float*)d_in[9];
    const float* Wf2 = (const float*)d_in[10];
    const float* bf2 = (const float*)d_in[11];
    float* out = (float*)d_out;

    char* ws = (char*)d_ws;
    auto al = [](size_t v) { return (v + 255) & ~(size_t)255; };
    size_t off = 0;
    int*   cnt  = (int*)(ws + off);   off = al(off + (size_t)NN * 4);
    float* dinv = (float*)(ws + off); off = al(off + (size_t)NN * 4);
    int*   csr  = (int*)(ws + off);   off = al(off + (size_t)NN * CAP * 4);
    float* A    = (float*)(ws + off); off = al(off + (size_t)NN * DD * 4);
    float* B    = (float*)(ws + off); off = al(off + (size_t)NN * DD * 4);

    hipMemsetAsync(cnt, 0, (size_t)NN * 4, stream);
    k_build<<<(EE + 255) / 256, 256, 0, stream>>>(ei, cnt, csr);
    k_dinv<<<(NN + 255) / 256, 256, 0, stream>>>(cnt, dinv);

    constexpr int ROWS = 16;
    int gw = (((NN + ROWS - 1) / ROWS) + 3) / 4;  // 4 waves/block
    int ga = (NN + 3) / 4;

    // layer 1: x -> A (h' = x@W1 * dinv), aggregate A -> B
    k_gemm_scale<ROWS><<<gw, 256, 0, stream>>>(x, W1, dinv, A);
    k_agg<<<ga, 256, 0, stream>>>(A, csr, cnt, dinv, b1, B);
    // layer 2
    k_gemm_scale<ROWS><<<gw, 256, 0, stream>>>(B, W2, dinv, A);
    k_agg<<<ga, 256, 0, stream>>>(A, csr, cnt, dinv, b2, B);
    // layer 3
    k_gemm_scale<ROWS><<<gw, 256, 0, stream>>>(B, W3, dinv, A);
    k_agg<<<ga, 256, 0, stream>>>(A, csr, cnt, dinv, b3, B);
    // FFN
    k_ffn<ROWS><<<gw, 256, 0, stream>>>(B, Wf1, bf1, Wf2, bf2, out);
}

// Round 2
// 567.513 us; speedup vs baseline: 1.2260x; 1.2260x over previous
//
#include <hip/hip_runtime.h>

#define NN   100000   // nodes
#define EE   1600000  // edges
#define DD   64       // feature dim
#define DOUT 16       // output dim
#define CAP  64       // max in-degree slots (Poisson(16): P(deg>64) ~ 1e-18)
#define NPW  8        // nodes per wave in fused kernels (amortize W preload)

// ---------------------------------------------------------------------------
// Build padded CSR-by-dst: cnt[d] = in-degree, csr[d*CAP + i] = i-th source.
// (Known hot: ~130us from 64B-line write amplification; candidate for a
//  binned two-pass scatter next round.)
// ---------------------------------------------------------------------------
__global__ __launch_bounds__(256) void k_build(const int* __restrict__ ei,
                                               int* __restrict__ cnt,
                                               int* __restrict__ csr) {
    int e = blockIdx.x * 256 + threadIdx.x;
    if (e >= EE) return;
    int s = ei[e];         // src row
    int d = ei[EE + e];    // dst row
    int pos = atomicAdd(&cnt[d], 1);
    if (pos < CAP) csr[d * CAP + pos] = s;
}

__global__ __launch_bounds__(256) void k_dinv(const int* __restrict__ cnt,
                                              float* __restrict__ dinv) {
    int n = blockIdx.x * 256 + threadIdx.x;
    if (n < NN) dinv[n] = rsqrtf((float)cnt[n] + 1.0f);
}

// ---------------------------------------------------------------------------
// hp[n][j] = (sum_k in[n][k] * W[k][j]) * dinv[n]   (layer-1 pre-transform)
// One wave per ROWS rows; lane j holds W column j; input row read as
// wave-uniform float4 broadcasts.
// ---------------------------------------------------------------------------
template <int ROWS>
__global__ __launch_bounds__(256) void k_gemm_scale(const float* __restrict__ in,
                                                    const float* __restrict__ W,
                                                    const float* __restrict__ dinv,
                                                    float* __restrict__ out) {
    const int lane = threadIdx.x & 63;
    const int wv   = threadIdx.x >> 6;
    float Wreg[DD];
#pragma unroll
    for (int k = 0; k < DD; ++k) Wreg[k] = W[k * DD + lane];  // coalesced

    int base = (blockIdx.x * 4 + wv) * ROWS;
    for (int r = 0; r < ROWS; ++r) {
        int n = base + r;
        if (n >= NN) return;
        const float4* row = (const float4*)(in + (size_t)n * DD);
        float acc = 0.f;
#pragma unroll
        for (int kk = 0; kk < DD / 4; ++kk) {
            float4 q = row[kk];  // uniform address -> broadcast
            acc = fmaf(q.x, Wreg[4 * kk + 0], acc);
            acc = fmaf(q.y, Wreg[4 * kk + 1], acc);
            acc = fmaf(q.z, Wreg[4 * kk + 2], acc);
            acc = fmaf(q.w, Wreg[4 * kk + 3], acc);
        }
        out[(size_t)n * DD + lane] = acc * dinv[n];
    }
}

// ---------------------------------------------------------------------------
// Fused layer: t = relu(dinv[n]*(hp[n] + sum_src hp[src]) + bias)
//              hpn[n] = (t @ Wn) * dinv[n]
// One wave per node (NPW nodes per wave, serial). Gather: 8-deep MLP,
// 64-lane x 4B coalesced row reads. Cross-lane for t@Wn: bounce t through a
// per-wave LDS slot, re-read as 16 wave-uniform float4 broadcasts.
// ---------------------------------------------------------------------------
__global__ __launch_bounds__(256) void k_fused(const float* __restrict__ hp,
                                               const int* __restrict__ csr,
                                               const int* __restrict__ cnt,
                                               const float* __restrict__ dinv,
                                               const float* __restrict__ bias,
                                               const float* __restrict__ Wn,
                                               float* __restrict__ hpn) {
    __shared__ float tbuf[4][DD];
    const int lane = threadIdx.x & 63;
    const int wv   = threadIdx.x >> 6;

    float Wreg[DD];
#pragma unroll
    for (int k = 0; k < DD; ++k) Wreg[k] = Wn[k * DD + lane];
    const float bv = bias[lane];

    int base = (blockIdx.x * 4 + wv) * NPW;
    for (int r = 0; r < NPW; ++r) {
        int n = base + r;
        if (n >= NN) return;
        int my = csr[(size_t)n * CAP + lane];  // coalesced index row
        int c  = cnt[n];
        if (c > CAP) c = CAP;
        float dv = dinv[n];

        float acc = hp[(size_t)n * DD + lane];  // self-loop term
        int i = 0;
        for (; i + 8 <= c; i += 8) {  // 8 outstanding gathers
            int s0 = __shfl(my, i + 0), s1 = __shfl(my, i + 1);
            int s2 = __shfl(my, i + 2), s3 = __shfl(my, i + 3);
            int s4 = __shfl(my, i + 4), s5 = __shfl(my, i + 5);
            int s6 = __shfl(my, i + 6), s7 = __shfl(my, i + 7);
            float a0 = hp[(size_t)s0 * DD + lane];
            float a1 = hp[(size_t)s1 * DD + lane];
            float a2 = hp[(size_t)s2 * DD + lane];
            float a3 = hp[(size_t)s3 * DD + lane];
            float a4 = hp[(size_t)s4 * DD + lane];
            float a5 = hp[(size_t)s5 * DD + lane];
            float a6 = hp[(size_t)s6 * DD + lane];
            float a7 = hp[(size_t)s7 * DD + lane];
            acc += ((a0 + a1) + (a2 + a3)) + ((a4 + a5) + (a6 + a7));
        }
        for (; i < c; ++i) {
            int s = __shfl(my, i);
            acc += hp[(size_t)s * DD + lane];
        }
        float t = fmaxf(fmaf(dv, acc, bv), 0.f);

        // t @ Wn via LDS round-trip (wave-private slot; in-wave dependences
        // order the ds ops; compiler inserts lgkmcnt waits).
        tbuf[wv][lane] = t;
        const float4* tb = (const float4*)tbuf[wv];
        float o = 0.f;
#pragma unroll
        for (int kk = 0; kk < DD / 4; ++kk) {
            float4 q = tb[kk];  // wave-uniform -> LDS broadcast
            o = fmaf(q.x, Wreg[4 * kk + 0], o);
            o = fmaf(q.y, Wreg[4 * kk + 1], o);
            o = fmaf(q.z, Wreg[4 * kk + 2], o);
            o = fmaf(q.w, Wreg[4 * kk + 3], o);
        }
        hpn[(size_t)n * DD + lane] = o * dv;
    }
}

// ---------------------------------------------------------------------------
// Final fused layer: t3 = relu(dinv*(agg)+b3); u = relu(t3@Wf1+bf1);
//                    out = u@Wf2 + bf2.
// ---------------------------------------------------------------------------
__global__ __launch_bounds__(256) void k_fused_ffn(const float* __restrict__ hp,
                                                   const int* __restrict__ csr,
                                                   const int* __restrict__ cnt,
                                                   const float* __restrict__ dinv,
                                                   const float* __restrict__ b3,
                                                   const float* __restrict__ Wf1,
                                                   const float* __restrict__ bf1,
                                                   const float* __restrict__ Wf2,
                                                   const float* __restrict__ bf2,
                                                   float* __restrict__ out) {
    __shared__ float tbuf[4][DD];
    __shared__ float ubuf[4][DD];
    const int lane = threadIdx.x & 63;
    const int wv   = threadIdx.x >> 6;
    const int q    = lane >> 4;   // quarter 0..3
    const int jj   = lane & 15;   // output feature

    float W1reg[DD];
#pragma unroll
    for (int k = 0; k < DD; ++k) W1reg[k] = Wf1[k * DD + lane];
    float W2reg[16];
#pragma unroll
    for (int kk = 0; kk < 16; ++kk) W2reg[kk] = Wf2[(q * 16 + kk) * DOUT + jj];
    const float b3v = b3[lane];
    const float b1v = bf1[lane];
    const float b2v = bf2[jj];

    int base = (blockIdx.x * 4 + wv) * NPW;
    for (int r = 0; r < NPW; ++r) {
        int n = base + r;
        if (n >= NN) return;
        int my = csr[(size_t)n * CAP + lane];
        int c  = cnt[n];
        if (c > CAP) c = CAP;
        float dv = dinv[n];

        float acc = hp[(size_t)n * DD + lane];
        int i = 0;
        for (; i + 8 <= c; i += 8) {
            int s0 = __shfl(my, i + 0), s1 = __shfl(my, i + 1);
            int s2 = __shfl(my, i + 2), s3 = __shfl(my, i + 3);
            int s4 = __shfl(my, i + 4), s5 = __shfl(my, i + 5);
            int s6 = __shfl(my, i + 6), s7 = __shfl(my, i + 7);
            float a0 = hp[(size_t)s0 * DD + lane];
            float a1 = hp[(size_t)s1 * DD + lane];
            float a2 = hp[(size_t)s2 * DD + lane];
            float a3 = hp[(size_t)s3 * DD + lane];
            float a4 = hp[(size_t)s4 * DD + lane];
            float a5 = hp[(size_t)s5 * DD + lane];
            float a6 = hp[(size_t)s6 * DD + lane];
            float a7 = hp[(size_t)s7 * DD + lane];
            acc += ((a0 + a1) + (a2 + a3)) + ((a4 + a5) + (a6 + a7));
        }
        for (; i < c; ++i) {
            int s = __shfl(my, i);
            acc += hp[(size_t)s * DD + lane];
        }
        float t = fmaxf(fmaf(dv, acc, b3v), 0.f);

        // u = relu(t @ Wf1 + bf1)
        tbuf[wv][lane] = t;
        const float4* tb = (const float4*)tbuf[wv];
        float u = b1v;
#pragma unroll
        for (int kk = 0; kk < DD / 4; ++kk) {
            float4 qd = tb[kk];
            u = fmaf(qd.x, W1reg[4 * kk + 0], u);
            u = fmaf(qd.y, W1reg[4 * kk + 1], u);
            u = fmaf(qd.z, W1reg[4 * kk + 2], u);
            u = fmaf(qd.w, W1reg[4 * kk + 3], u);
        }
        u = fmaxf(u, 0.f);

        // out = u @ Wf2 + bf2 : lane (q,jj) does quarter-K partial, 2 xor-reduces
        ubuf[wv][lane] = u;
        const float4* ub = (const float4*)(ubuf[wv] + q * 16);
        float p = 0.f;
#pragma unroll
        for (int kk = 0; kk < 4; ++kk) {
            float4 z = ub[kk];  // group-uniform -> broadcast within 16-lane group
            p = fmaf(z.x, W2reg[4 * kk + 0], p);
            p = fmaf(z.y, W2reg[4 * kk + 1], p);
            p = fmaf(z.z, W2reg[4 * kk + 2], p);
            p = fmaf(z.w, W2reg[4 * kk + 3], p);
        }
        p += __shfl_xor(p, 16);
        p += __shfl_xor(p, 32);
        if (lane < 16) out[(size_t)n * DOUT + jj] = p + b2v;
    }
}

// ---------------------------------------------------------------------------
extern "C" void kernel_launch(void* const* d_in, const int* in_sizes, int n_in,
                              void* d_out, int out_size, void* d_ws, size_t ws_size,
                              hipStream_t stream) {
    const float* x   = (const float*)d_in[0];
    const int*   ei  = (const int*)d_in[1];
    const float* W1  = (const float*)d_in[2];
    const float* b1  = (const float*)d_in[3];
    const float* W2  = (const float*)d_in[4];
    const float* b2  = (const float*)d_in[5];
    const float* W3  = (const float*)d_in[6];
    const float* b3  = (const float*)d_in[7];
    const float* Wf1 = (const float*)d_in[8];
    const float* bf1 = (const float*)d_in[9];
    const float* Wf2 = (const float*)d_in[10];
    const float* bf2 = (const float*)d_in[11];
    float* out = (float*)d_out;

    char* ws = (char*)d_ws;
    auto al = [](size_t v) { return (v + 255) & ~(size_t)255; };
    size_t off = 0;
    int*   cnt  = (int*)(ws + off);   off = al(off + (size_t)NN * 4);
    float* dinv = (float*)(ws + off); off = al(off + (size_t)NN * 4);
    int*   csr  = (int*)(ws + off);   off = al(off + (size_t)NN * CAP * 4);
    float* A    = (float*)(ws + off); off = al(off + (size_t)NN * DD * 4);
    float* B    = (float*)(ws + off); off = al(off + (size_t)NN * DD * 4);

    hipMemsetAsync(cnt, 0, (size_t)NN * 4, stream);
    k_build<<<(EE + 255) / 256, 256, 0, stream>>>(ei, cnt, csr);
    k_dinv<<<(NN + 255) / 256, 256, 0, stream>>>(cnt, dinv);

    constexpr int ROWS = 16;
    int gg = (((NN + ROWS - 1) / ROWS) + 3) / 4;   // gemm grid (4 waves/block)
    int gf = (NN + 4 * NPW - 1) / (4 * NPW);       // fused grid: 3125 blocks

    // layer 1 pre-transform: hp1 = (x@W1)*dinv
    k_gemm_scale<ROWS><<<gg, 256, 0, stream>>>(x, W1, dinv, A);
    // fused layer 1->2: agg(hp1)+relu+b1, then hp2 = (t@W2)*dinv
    k_fused<<<gf, 256, 0, stream>>>(A, csr, cnt, dinv, b1, W2, B);
    // fused layer 2->3: agg(hp2)+relu+b2, then hp3 = (t@W3)*dinv
    k_fused<<<gf, 256, 0, stream>>>(B, csr, cnt, dinv, b2, W3, A);
    // fused layer 3 + FFN -> out
    k_fused_ffn<<<gf, 256, 0, stream>>>(A, csr, cnt, dinv, b3, Wf1, bf1, Wf2, bf2, out);
}